// Round 1
// baseline (1593.540 us; speedup 1.0000x reference)
//
#include <hip/hip_runtime.h>
#include <hip/hip_bf16.h>
#include <math.h>

// ---------------------------------------------------------------------------
// GCN layer: out = tanh( scatter_add(adj_vals * h[src] -> dst)
//                        + seq @ w_proj + b_proj + bias ),   h = seq @ w_fc
// N=100000, E=1600000, D_IN=D_OUT=128, all fp32.
// Plan (round 0, correctness + sane perf):
//   K1: h    = seq @ w_fc            -> d_ws           (tiled LDS matmul)
//   K2: base = seq @ w_proj + biases -> d_out          (same kernel, bias on)
//   K3: edge scatter: atomicAdd(d_out[dst] += val * h[src]) (1 edge / wave)
//   K4: d_out = tanh(d_out)
// ---------------------------------------------------------------------------

#define MT 32  // rows (nodes) per matmul block

// 256 threads: thread t -> 2 cols c2=(t&63)*2, 8 rows r0=(t>>6)*8.
// LDS: w [128x128] = 64 KB + seq tile [32x128] = 16 KB = 80 KB -> 2 blocks/CU.
__global__ __launch_bounds__(256, 2)
void mm_kernel(const float* __restrict__ seq, const float* __restrict__ w,
               const float* __restrict__ b0p, const float* __restrict__ b1p,
               float* __restrict__ out, int N, int add_bias) {
    __shared__ __align__(16) float ws_[128 * 128];   // [k][c]
    __shared__ __align__(16) float ss[MT][128];      // [row][k]
    const int tid = threadIdx.x;

    // stage w: 4096 float4 / 256 threads = 16 each, coalesced
    {
        const float4* w4 = (const float4*)w;
        float4* d4 = (float4*)ws_;
        for (int i = tid; i < 128 * 128 / 4; i += 256) d4[i] = w4[i];
    }
    const int row0 = blockIdx.x * MT;
    const int rows = (N - row0 < MT) ? (N - row0) : MT;
    // stage seq tile: rows*32 float4
    {
        const float4* s4 = (const float4*)(seq + (size_t)row0 * 128);
        float4* d4 = (float4*)&ss[0][0];
        const int lim = rows * 32;
        for (int i = tid; i < lim; i += 256) d4[i] = s4[i];
    }
    __syncthreads();

    const int c2 = (tid & 63) * 2;
    const int r0 = (tid >> 6) * 8;
    float acc[8][2] = {};

    #pragma unroll 4
    for (int k = 0; k < 128; k += 4) {
        float2 wv[4];
        #pragma unroll
        for (int kk = 0; kk < 4; kk++)
            wv[kk] = *(const float2*)&ws_[(k + kk) * 128 + c2];
        #pragma unroll
        for (int r = 0; r < 8; r++) {
            float4 sv = *(const float4*)&ss[r0 + r][k];   // broadcast within wave
            acc[r][0] += sv.x * wv[0].x + sv.y * wv[1].x + sv.z * wv[2].x + sv.w * wv[3].x;
            acc[r][1] += sv.x * wv[0].y + sv.y * wv[1].y + sv.z * wv[2].y + sv.w * wv[3].y;
        }
    }

    float badd0 = 0.f, badd1 = 0.f;
    if (add_bias) {
        badd0 = b0p[c2] + b1p[c2];
        badd1 = b0p[c2 + 1] + b1p[c2 + 1];
    }
    #pragma unroll
    for (int r = 0; r < 8; r++) {
        int row = row0 + r0 + r;
        if (row < N) {
            float2 v = make_float2(acc[r][0] + badd0, acc[r][1] + badd1);
            *(float2*)&out[(size_t)row * 128 + c2] = v;
        }
    }
}

// One edge per wave iteration; lane l handles cols 2l, 2l+1 (float2 gather).
__global__ __launch_bounds__(256)
void edge_scatter(const int* __restrict__ esrc, const int* __restrict__ edst,
                  const float* __restrict__ vals, const float* __restrict__ h,
                  float* __restrict__ out, int E) {
    const int gtid = blockIdx.x * blockDim.x + threadIdx.x;
    const int wave = gtid >> 6;
    const int lane = threadIdx.x & 63;
    const int nw = (gridDim.x * blockDim.x) >> 6;
    for (int e = wave; e < E; e += nw) {
        const int s = esrc[e];
        const int d = edst[e];
        const float v = vals[e];
        float2 hv = *(const float2*)(h + (size_t)s * 128 + lane * 2);
        float* op = out + (size_t)d * 128 + lane * 2;
        atomicAdd(op,     v * hv.x);
        atomicAdd(op + 1, v * hv.y);
    }
}

__global__ __launch_bounds__(256)
void tanh_kernel(float* __restrict__ out, int n4) {
    const int i = blockIdx.x * blockDim.x + threadIdx.x;
    if (i < n4) {
        float4 v = ((float4*)out)[i];
        v.x = tanhf(v.x);
        v.y = tanhf(v.y);
        v.z = tanhf(v.z);
        v.w = tanhf(v.w);
        ((float4*)out)[i] = v;
    }
}

extern "C" void kernel_launch(void* const* d_in, const int* in_sizes, int n_in,
                              void* d_out, int out_size, void* d_ws, size_t ws_size,
                              hipStream_t stream) {
    const float* seq    = (const float*)d_in[0];
    const int*   esrc   = (const int*)  d_in[1];
    const int*   edst   = (const int*)  d_in[2];
    const float* vals   = (const float*)d_in[3];
    const float* w_fc   = (const float*)d_in[4];
    const float* w_proj = (const float*)d_in[5];
    const float* b_proj = (const float*)d_in[6];
    const float* bias   = (const float*)d_in[7];
    float* out = (float*)d_out;
    float* h   = (float*)d_ws;   // N*128 fp32 = 51.2 MB scratch

    const int N = in_sizes[0] / 128;
    const int E = in_sizes[1];

    const int mm_blocks = (N + MT - 1) / MT;
    // K1: h = seq @ w_fc
    mm_kernel<<<mm_blocks, 256, 0, stream>>>(seq, w_fc, nullptr, nullptr, h, N, 0);
    // K2: out = seq @ w_proj + b_proj + bias   (accumulation base)
    mm_kernel<<<mm_blocks, 256, 0, stream>>>(seq, w_proj, b_proj, bias, out, N, 1);
    // K3: out[dst] += val * h[src]
    edge_scatter<<<8192, 256, 0, stream>>>(esrc, edst, vals, h, out, E);
    // K4: out = tanh(out)
    const int n4 = (N * 128) / 4;
    tanh_kernel<<<(n4 + 255) / 256, 256, 0, stream>>>(out, n4);
}

// Round 2
// 596.583 us; speedup vs baseline: 2.6711x; 2.6711x over previous
//
#include <hip/hip_runtime.h>
#include <hip/hip_bf16.h>
#include <math.h>

// ---------------------------------------------------------------------------
// GCN layer: out = tanh( scatter_add(adj_vals * h[src] -> dst)
//                        + seq @ w_proj + b_proj + bias ),   h = seq @ w_fc
// N=100000, E=1600000, D=128, fp32.
// R1: replace fp32-atomic edge_scatter (1299 us, atomic-latency bound,
//     VALUBusy 2.8%) with device-built CSR-by-dst + one-wave-per-node
//     gather-reduce, fused tanh epilogue. No fp32 atomics anywhere.
// ---------------------------------------------------------------------------

#define MT 32  // rows (nodes) per matmul block

// 256 threads: thread t -> 2 cols c2=(t&63)*2, 8 rows r0=(t>>6)*8.
// LDS: w [128x128] = 64 KB + seq tile [32x128] = 16 KB = 80 KB -> 2 blocks/CU.
__global__ __launch_bounds__(256, 2)
void mm_kernel(const float* __restrict__ seq, const float* __restrict__ w,
               const float* __restrict__ b0p, const float* __restrict__ b1p,
               float* __restrict__ out, int N, int add_bias) {
    __shared__ __align__(16) float ws_[128 * 128];   // [k][c]
    __shared__ __align__(16) float ss[MT][128];      // [row][k]
    const int tid = threadIdx.x;

    {
        const float4* w4 = (const float4*)w;
        float4* d4 = (float4*)ws_;
        for (int i = tid; i < 128 * 128 / 4; i += 256) d4[i] = w4[i];
    }
    const int row0 = blockIdx.x * MT;
    const int rows = (N - row0 < MT) ? (N - row0) : MT;
    {
        const float4* s4 = (const float4*)(seq + (size_t)row0 * 128);
        float4* d4 = (float4*)&ss[0][0];
        const int lim = rows * 32;
        for (int i = tid; i < lim; i += 256) d4[i] = s4[i];
    }
    __syncthreads();

    const int c2 = (tid & 63) * 2;
    const int r0 = (tid >> 6) * 8;
    float acc[8][2] = {};

    #pragma unroll 4
    for (int k = 0; k < 128; k += 4) {
        float2 wv[4];
        #pragma unroll
        for (int kk = 0; kk < 4; kk++)
            wv[kk] = *(const float2*)&ws_[(k + kk) * 128 + c2];
        #pragma unroll
        for (int r = 0; r < 8; r++) {
            float4 sv = *(const float4*)&ss[r0 + r][k];
            acc[r][0] += sv.x * wv[0].x + sv.y * wv[1].x + sv.z * wv[2].x + sv.w * wv[3].x;
            acc[r][1] += sv.x * wv[0].y + sv.y * wv[1].y + sv.z * wv[2].y + sv.w * wv[3].y;
        }
    }

    float badd0 = 0.f, badd1 = 0.f;
    if (add_bias) {
        badd0 = b0p[c2] + b1p[c2];
        badd1 = b0p[c2 + 1] + b1p[c2 + 1];
    }
    #pragma unroll
    for (int r = 0; r < 8; r++) {
        int row = row0 + r0 + r;
        if (row < N) {
            float2 v = make_float2(acc[r][0] + badd0, acc[r][1] + badd1);
            *(float2*)&out[(size_t)row * 128 + c2] = v;
        }
    }
}

// ---------------- CSR build ----------------

__global__ __launch_bounds__(256)
void hist_kernel(const int* __restrict__ edst, int* __restrict__ deg, int E) {
    const int stride = gridDim.x * blockDim.x;
    for (int e = blockIdx.x * blockDim.x + threadIdx.x; e < E; e += stride)
        atomicAdd(&deg[edst[e]], 1);
}

// Block b scans deg[b*1024 .. b*1024+1023] inclusively into off1[] (= off+1),
// writes block total to bsum[b]. 256 threads x 4 elems.
__global__ __launch_bounds__(256)
void scan1_kernel(const int* __restrict__ deg, int* __restrict__ off1,
                  int* __restrict__ bsum, int N) {
    __shared__ int s[256];
    const int t = threadIdx.x;
    const int base = blockIdx.x * 1024 + t * 4;
    int v0 = (base + 0 < N) ? deg[base + 0] : 0;
    int v1 = (base + 1 < N) ? deg[base + 1] : 0;
    int v2 = (base + 2 < N) ? deg[base + 2] : 0;
    int v3 = (base + 3 < N) ? deg[base + 3] : 0;
    const int mysum = v0 + v1 + v2 + v3;
    s[t] = mysum;
    __syncthreads();
    for (int o = 1; o < 256; o <<= 1) {
        int add = (t >= o) ? s[t - o] : 0;
        __syncthreads();
        s[t] += add;
        __syncthreads();
    }
    const int excl = s[t] - mysum;
    int a0 = excl + v0, a1 = a0 + v1, a2 = a1 + v2, a3 = a2 + v3;
    if (base + 0 < N) off1[base + 0] = a0;
    if (base + 1 < N) off1[base + 1] = a1;
    if (base + 2 < N) off1[base + 2] = a2;
    if (base + 3 < N) off1[base + 3] = a3;
    if (t == 255) bsum[blockIdx.x] = s[255];
}

// Single block: exclusive-scan nb (<=128) block sums.
__global__ __launch_bounds__(128)
void scan2_kernel(const int* __restrict__ bsum, int* __restrict__ ebsum, int nb) {
    __shared__ int s[128];
    const int t = threadIdx.x;
    const int v = (t < nb) ? bsum[t] : 0;
    s[t] = v;
    __syncthreads();
    for (int o = 1; o < 128; o <<= 1) {
        int add = (t >= o) ? s[t - o] : 0;
        __syncthreads();
        s[t] += add;
        __syncthreads();
    }
    if (t < nb) ebsum[t] = s[t] - v;
}

// off[1+idx] += ebsum[block]; off[0] = 0; cursor[idx] = row start
// (cursor currently holds deg; start = final off[1+idx] - deg[idx]).
__global__ __launch_bounds__(256)
void addback_kernel(int* __restrict__ off, int* __restrict__ cursor_deg,
                    const int* __restrict__ ebsum, int N) {
    const int add = ebsum[blockIdx.x];
    const int base = blockIdx.x * 1024 + threadIdx.x * 4;
    if (blockIdx.x == 0 && threadIdx.x == 0) off[0] = 0;
    #pragma unroll
    for (int j = 0; j < 4; j++) {
        const int idx = base + j;
        if (idx < N) {
            const int v = off[1 + idx] + add;
            off[1 + idx] = v;
            cursor_deg[idx] = v - cursor_deg[idx];
        }
    }
}

__global__ __launch_bounds__(256)
void scatter_kernel(const int* __restrict__ esrc, const int* __restrict__ edst,
                    const float* __restrict__ vals, int* __restrict__ cursor,
                    int* __restrict__ ssrc, float* __restrict__ sval, int E) {
    const int stride = gridDim.x * blockDim.x;
    for (int e = blockIdx.x * blockDim.x + threadIdx.x; e < E; e += stride) {
        const int d = edst[e];
        const int p = atomicAdd(&cursor[d], 1);
        ssrc[p] = esrc[e];
        sval[p] = vals[e];
    }
}

// One wave per dst node. Lane l covers cols [2l, 2l+1]. Edge (src,val) pairs
// are loaded 64-at-a-time lane-parallel, then broadcast via shfl so the h-row
// gather is the only per-iteration memory op. Fused tanh(agg + base) epilogue.
__global__ __launch_bounds__(256)
void aggregate_kernel(const int* __restrict__ off, const int* __restrict__ ssrc,
                      const float* __restrict__ sval, const float* __restrict__ h,
                      float* __restrict__ out, int N) {
    const int gtid = blockIdx.x * 256 + threadIdx.x;
    const int node = gtid >> 6;
    const int lane = threadIdx.x & 63;
    if (node >= N) return;
    const int beg = off[node];
    const int end = off[node + 1];
    const float2* hp = (const float2*)h;
    float2 acc = make_float2(0.f, 0.f);
    for (int b0 = beg; b0 < end; b0 += 64) {
        const int rem = end - b0;
        const int cnt = rem < 64 ? rem : 64;
        int es = 0;
        float ev = 0.f;
        if (lane < cnt) {
            es = ssrc[b0 + lane];
            ev = sval[b0 + lane];
        }
        for (int j = 0; j < cnt; j++) {
            const int s = __shfl(es, j);
            const float v = __shfl(ev, j);
            const float2 hv = hp[(size_t)s * 64 + lane];
            acc.x += v * hv.x;
            acc.y += v * hv.y;
        }
    }
    float2 basev = ((const float2*)out)[(size_t)node * 64 + lane];
    float2 r;
    r.x = tanhf(acc.x + basev.x);
    r.y = tanhf(acc.y + basev.y);
    ((float2*)out)[(size_t)node * 64 + lane] = r;
}

// ---------------- fallback (atomic) path, used only if ws too small --------

__global__ __launch_bounds__(256)
void edge_scatter(const int* __restrict__ esrc, const int* __restrict__ edst,
                  const float* __restrict__ vals, const float* __restrict__ h,
                  float* __restrict__ out, int E) {
    const int gtid = blockIdx.x * blockDim.x + threadIdx.x;
    const int wave = gtid >> 6;
    const int lane = threadIdx.x & 63;
    const int nw = (gridDim.x * blockDim.x) >> 6;
    for (int e = wave; e < E; e += nw) {
        const int s = esrc[e];
        const int d = edst[e];
        const float v = vals[e];
        float2 hv = *(const float2*)(h + (size_t)s * 128 + lane * 2);
        float* op = out + (size_t)d * 128 + lane * 2;
        atomicAdd(op, v * hv.x);
        atomicAdd(op + 1, v * hv.y);
    }
}

__global__ __launch_bounds__(256)
void tanh_kernel(float* __restrict__ out, int n4) {
    const int i = blockIdx.x * blockDim.x + threadIdx.x;
    if (i < n4) {
        float4 v = ((float4*)out)[i];
        v.x = tanhf(v.x);
        v.y = tanhf(v.y);
        v.z = tanhf(v.z);
        v.w = tanhf(v.w);
        ((float4*)out)[i] = v;
    }
}

static inline size_t align16(size_t x) { return (x + 15) & ~(size_t)15; }

extern "C" void kernel_launch(void* const* d_in, const int* in_sizes, int n_in,
                              void* d_out, int out_size, void* d_ws, size_t ws_size,
                              hipStream_t stream) {
    const float* seq    = (const float*)d_in[0];
    const int*   esrc   = (const int*)  d_in[1];
    const int*   edst   = (const int*)  d_in[2];
    const float* vals   = (const float*)d_in[3];
    const float* w_fc   = (const float*)d_in[4];
    const float* w_proj = (const float*)d_in[5];
    const float* b_proj = (const float*)d_in[6];
    const float* bias   = (const float*)d_in[7];
    float* out = (float*)d_out;

    const int N = in_sizes[0] / 128;
    const int E = in_sizes[1];

    // workspace layout
    char* ws = (char*)d_ws;
    const size_t o_h    = 0;                                   // N*128 f32
    const size_t o_off  = align16(o_h    + (size_t)N * 128 * 4); // (N+1) i32
    const size_t o_cur  = align16(o_off  + (size_t)(N + 1) * 4); // N i32 (deg->cursor)
    const size_t o_bs   = align16(o_cur  + (size_t)N * 4);       // 128 i32
    const size_t o_ebs  = align16(o_bs   + 512);                 // 128 i32
    const size_t o_ssrc = align16(o_ebs  + 512);                 // E i32
    const size_t o_sval = align16(o_ssrc + (size_t)E * 4);       // E f32
    const size_t need   = o_sval + (size_t)E * 4;

    float* h      = (float*)(ws + o_h);
    int*   off    = (int*)  (ws + o_off);
    int*   cursor = (int*)  (ws + o_cur);
    int*   bsum   = (int*)  (ws + o_bs);
    int*   ebsum  = (int*)  (ws + o_ebs);
    int*   ssrc   = (int*)  (ws + o_ssrc);
    float* sval   = (float*)(ws + o_sval);

    const int nb1 = (N + 1023) / 1024;   // scan1 blocks (98 for N=100000)
    const int mm_blocks = (N + MT - 1) / MT;

    // K1: h = seq @ w_fc
    mm_kernel<<<mm_blocks, 256, 0, stream>>>(seq, w_fc, nullptr, nullptr, h, N, 0);
    // K2: out = seq @ w_proj + b_proj + bias
    mm_kernel<<<mm_blocks, 256, 0, stream>>>(seq, w_proj, b_proj, bias, out, N, 1);

    if (ws_size >= need && nb1 <= 128) {
        // CSR-by-dst build + gather-reduce
        hipMemsetAsync(cursor, 0, (size_t)N * 4, stream);
        hist_kernel<<<2048, 256, 0, stream>>>(edst, cursor, E);
        scan1_kernel<<<nb1, 256, 0, stream>>>(cursor, off + 1, bsum, N);
        scan2_kernel<<<1, 128, 0, stream>>>(bsum, ebsum, nb1);
        addback_kernel<<<nb1, 256, 0, stream>>>(off, cursor, ebsum, N);
        scatter_kernel<<<2048, 256, 0, stream>>>(esrc, edst, vals, cursor, ssrc, sval, E);
        const int agg_blocks = (N * 64 + 255) / 256;
        aggregate_kernel<<<agg_blocks, 256, 0, stream>>>(off, ssrc, sval, h, out, N);
    } else {
        // fallback: fp32 atomics
        edge_scatter<<<8192, 256, 0, stream>>>(esrc, edst, vals, h, out, E);
        const int n4 = (N * 128) / 4;
        tanh_kernel<<<(n4 + 255) / 256, 256, 0, stream>>>(out, n4);
    }
}

// Round 3
// 559.453 us; speedup vs baseline: 2.8484x; 1.0664x over previous
//
#include <hip/hip_runtime.h>
#include <math.h>

// ---------------------------------------------------------------------------
// GCN layer: out = tanh( scatter_add(adj_vals * h[src] -> dst)
//                        + seq @ w_proj + b_proj + bias ),   h = seq @ w_fc
// N=100000, E=1600000, D=128, fp32.
// R2 -> R3:
//  * mm: fp32 vector (LDS-bound, ~120us each) -> MFMA bf16 split hi/lo
//    (A*B ~= Ah*Bh + Ah*Bl + Al*Bh, rel err ~1e-5), HBM-streaming.
//  * scatter: (src,val) packed as one int2 store (halve random-store count;
//    R2 showed 154 MB writeback for 25.6 MB payload).
//  * aggregate: unchanged (at delivered-BW bound ~6.3 TB/s on 819 MB gather).
// ---------------------------------------------------------------------------

typedef __attribute__((ext_vector_type(8))) short short8;
typedef __attribute__((ext_vector_type(4))) float float4v;

static __device__ __forceinline__ short f2bf(float x) {
    unsigned u = __float_as_uint(x);
    unsigned r = (u + 0x7fffu + ((u >> 16) & 1u)) >> 16;   // RNE
    return (short)r;
}
static __device__ __forceinline__ float bf2f(short h) {
    return __uint_as_float(((unsigned)(unsigned short)h) << 16);
}

// ---------------- MFMA matmul: out[N x 128] = seq[N x 128] @ w[128 x 128] ---
// Block: 256 thr = 4 waves; 64 rows/block (16 per wave), all 128 cols.
// W staged in LDS as transposed bf16 hi/lo: wt[c][k], row stride KP=136
// (16B-aligned rows). A fragments converted fp32->hi/lo bf16 in registers.
#define KP 136

__global__ __launch_bounds__(256, 2)
void mm_mfma_kernel(const float* __restrict__ seq, const float* __restrict__ w,
                    const float* __restrict__ b0p, const float* __restrict__ b1p,
                    float* __restrict__ out, int N, int add_bias) {
    __shared__ short wt_hi[128 * KP];
    __shared__ short wt_lo[128 * KP];

    const int tid = threadIdx.x;
    // stage + convert w (w[k][c] row-major) -> wt_*[c][k]
    {
        const float4* w4 = (const float4*)w;
        for (int i = tid; i < 4096; i += 256) {
            const int k  = i >> 5;
            const int c4 = (i & 31) * 4;
            float4 v = w4[i];
            float xs[4] = {v.x, v.y, v.z, v.w};
            #pragma unroll
            for (int j = 0; j < 4; j++) {
                const float x = xs[j];
                const short hi = f2bf(x);
                const short lo = f2bf(x - bf2f(hi));
                wt_hi[(c4 + j) * KP + k] = hi;
                wt_lo[(c4 + j) * KP + k] = lo;
            }
        }
    }
    __syncthreads();

    const int wave = tid >> 6;
    const int lane = tid & 63;
    const int q = lane >> 4;        // quad 0..3
    const int c = lane & 15;        // 0..15
    const int R = blockIdx.x * 64 + wave * 16;   // wave's row base
    const int rowL = (R + c < N) ? (R + c) : (N - 1);   // clamped load row

    float4v acc[8];
    #pragma unroll
    for (int ct = 0; ct < 8; ct++) acc[ct] = (float4v){0.f, 0.f, 0.f, 0.f};

    #pragma unroll
    for (int t = 0; t < 4; t++) {              // k-steps of 32
        const int kk = t * 32 + q * 8;
        const float4 a0 = *(const float4*)&seq[(size_t)rowL * 128 + kk];
        const float4 a1 = *(const float4*)&seq[(size_t)rowL * 128 + kk + 4];
        float xs[8] = {a0.x, a0.y, a0.z, a0.w, a1.x, a1.y, a1.z, a1.w};
        union { short s[8]; short8 v; } ahi, alo;
        #pragma unroll
        for (int j = 0; j < 8; j++) {
            const short hi = f2bf(xs[j]);
            ahi.s[j] = hi;
            alo.s[j] = f2bf(xs[j] - bf2f(hi));
        }
        #pragma unroll
        for (int ct = 0; ct < 8; ct++) {
            const int n = ct * 16 + c;
            const short8 bhi = *(const short8*)&wt_hi[n * KP + kk];
            const short8 blo = *(const short8*)&wt_lo[n * KP + kk];
            acc[ct] = __builtin_amdgcn_mfma_f32_16x16x32_bf16(ahi.v, bhi, acc[ct], 0, 0, 0);
            acc[ct] = __builtin_amdgcn_mfma_f32_16x16x32_bf16(ahi.v, blo, acc[ct], 0, 0, 0);
            acc[ct] = __builtin_amdgcn_mfma_f32_16x16x32_bf16(alo.v, bhi, acc[ct], 0, 0, 0);
        }
    }

    // epilogue: C/D layout col = lane&15, row = quad*4 + reg
    #pragma unroll
    for (int ct = 0; ct < 8; ct++) {
        const int col = ct * 16 + c;
        float badd = 0.f;
        if (add_bias) badd = b0p[col] + b1p[col];
        #pragma unroll
        for (int r = 0; r < 4; r++) {
            const int row = R + q * 4 + r;
            if (row < N) out[(size_t)row * 128 + col] = acc[ct][r] + badd;
        }
    }
}

// ---------------- CSR build ----------------

__global__ __launch_bounds__(256)
void hist_kernel(const int* __restrict__ edst, int* __restrict__ deg, int E) {
    const int stride = gridDim.x * blockDim.x;
    for (int e = blockIdx.x * blockDim.x + threadIdx.x; e < E; e += stride)
        atomicAdd(&deg[edst[e]], 1);
}

__global__ __launch_bounds__(256)
void scan1_kernel(const int* __restrict__ deg, int* __restrict__ off1,
                  int* __restrict__ bsum, int N) {
    __shared__ int s[256];
    const int t = threadIdx.x;
    const int base = blockIdx.x * 1024 + t * 4;
    int v0 = (base + 0 < N) ? deg[base + 0] : 0;
    int v1 = (base + 1 < N) ? deg[base + 1] : 0;
    int v2 = (base + 2 < N) ? deg[base + 2] : 0;
    int v3 = (base + 3 < N) ? deg[base + 3] : 0;
    const int mysum = v0 + v1 + v2 + v3;
    s[t] = mysum;
    __syncthreads();
    for (int o = 1; o < 256; o <<= 1) {
        int add = (t >= o) ? s[t - o] : 0;
        __syncthreads();
        s[t] += add;
        __syncthreads();
    }
    const int excl = s[t] - mysum;
    int a0 = excl + v0, a1 = a0 + v1, a2 = a1 + v2, a3 = a2 + v3;
    if (base + 0 < N) off1[base + 0] = a0;
    if (base + 1 < N) off1[base + 1] = a1;
    if (base + 2 < N) off1[base + 2] = a2;
    if (base + 3 < N) off1[base + 3] = a3;
    if (t == 255) bsum[blockIdx.x] = s[255];
}

__global__ __launch_bounds__(128)
void scan2_kernel(const int* __restrict__ bsum, int* __restrict__ ebsum, int nb) {
    __shared__ int s[128];
    const int t = threadIdx.x;
    const int v = (t < nb) ? bsum[t] : 0;
    s[t] = v;
    __syncthreads();
    for (int o = 1; o < 128; o <<= 1) {
        int add = (t >= o) ? s[t - o] : 0;
        __syncthreads();
        s[t] += add;
        __syncthreads();
    }
    if (t < nb) ebsum[t] = s[t] - v;
}

__global__ __launch_bounds__(256)
void addback_kernel(int* __restrict__ off, int* __restrict__ cursor_deg,
                    const int* __restrict__ ebsum, int N) {
    const int add = ebsum[blockIdx.x];
    const int base = blockIdx.x * 1024 + threadIdx.x * 4;
    if (blockIdx.x == 0 && threadIdx.x == 0) off[0] = 0;
    #pragma unroll
    for (int j = 0; j < 4; j++) {
        const int idx = base + j;
        if (idx < N) {
            const int v = off[1 + idx] + add;
            off[1 + idx] = v;
            cursor_deg[idx] = v - cursor_deg[idx];
        }
    }
}

// (src, val) packed into one int2 -> single 8B random store per edge.
__global__ __launch_bounds__(256)
void scatter_kernel(const int* __restrict__ esrc, const int* __restrict__ edst,
                    const float* __restrict__ vals, int* __restrict__ cursor,
                    int2* __restrict__ sedge, int E) {
    const int stride = gridDim.x * blockDim.x;
    for (int e = blockIdx.x * blockDim.x + threadIdx.x; e < E; e += stride) {
        const int d = edst[e];
        const int p = atomicAdd(&cursor[d], 1);
        sedge[p] = make_int2(esrc[e], __float_as_int(vals[e]));
    }
}

// One wave per dst node; lane l covers cols [2l, 2l+1]; fused tanh epilogue.
__global__ __launch_bounds__(256)
void aggregate_kernel(const int* __restrict__ off, const int2* __restrict__ sedge,
                      const float* __restrict__ h, float* __restrict__ out, int N) {
    const int gtid = blockIdx.x * 256 + threadIdx.x;
    const int node = gtid >> 6;
    const int lane = threadIdx.x & 63;
    if (node >= N) return;
    const int beg = off[node];
    const int end = off[node + 1];
    const float2* hp = (const float2*)h;
    float2 acc = make_float2(0.f, 0.f);
    for (int b0 = beg; b0 < end; b0 += 64) {
        const int rem = end - b0;
        const int cnt = rem < 64 ? rem : 64;
        int es = 0;
        float ev = 0.f;
        if (lane < cnt) {
            const int2 p = sedge[b0 + lane];
            es = p.x;
            ev = __int_as_float(p.y);
        }
        for (int j = 0; j < cnt; j++) {
            const int s = __shfl(es, j);
            const float v = __shfl(ev, j);
            const float2 hv = hp[(size_t)s * 64 + lane];
            acc.x += v * hv.x;
            acc.y += v * hv.y;
        }
    }
    float2 basev = ((const float2*)out)[(size_t)node * 64 + lane];
    float2 r;
    r.x = tanhf(acc.x + basev.x);
    r.y = tanhf(acc.y + basev.y);
    ((float2*)out)[(size_t)node * 64 + lane] = r;
}

// ---------------- fallback (atomic) path, used only if ws too small --------

__global__ __launch_bounds__(256)
void edge_scatter(const int* __restrict__ esrc, const int* __restrict__ edst,
                  const float* __restrict__ vals, const float* __restrict__ h,
                  float* __restrict__ out, int E) {
    const int gtid = blockIdx.x * blockDim.x + threadIdx.x;
    const int wave = gtid >> 6;
    const int lane = threadIdx.x & 63;
    const int nw = (gridDim.x * blockDim.x) >> 6;
    for (int e = wave; e < E; e += nw) {
        const int s = esrc[e];
        const int d = edst[e];
        const float v = vals[e];
        float2 hv = *(const float2*)(h + (size_t)s * 128 + lane * 2);
        float* op = out + (size_t)d * 128 + lane * 2;
        atomicAdd(op, v * hv.x);
        atomicAdd(op + 1, v * hv.y);
    }
}

__global__ __launch_bounds__(256)
void tanh_kernel(float* __restrict__ out, int n4) {
    const int i = blockIdx.x * blockDim.x + threadIdx.x;
    if (i < n4) {
        float4 v = ((float4*)out)[i];
        v.x = tanhf(v.x);
        v.y = tanhf(v.y);
        v.z = tanhf(v.z);
        v.w = tanhf(v.w);
        ((float4*)out)[i] = v;
    }
}

static inline size_t align16(size_t x) { return (x + 15) & ~(size_t)15; }

extern "C" void kernel_launch(void* const* d_in, const int* in_sizes, int n_in,
                              void* d_out, int out_size, void* d_ws, size_t ws_size,
                              hipStream_t stream) {
    const float* seq    = (const float*)d_in[0];
    const int*   esrc   = (const int*)  d_in[1];
    const int*   edst   = (const int*)  d_in[2];
    const float* vals   = (const float*)d_in[3];
    const float* w_fc   = (const float*)d_in[4];
    const float* w_proj = (const float*)d_in[5];
    const float* b_proj = (const float*)d_in[6];
    const float* bias   = (const float*)d_in[7];
    float* out = (float*)d_out;

    const int N = in_sizes[0] / 128;
    const int E = in_sizes[1];

    // workspace layout
    char* ws = (char*)d_ws;
    const size_t o_h    = 0;                                     // N*128 f32
    const size_t o_off  = align16(o_h    + (size_t)N * 128 * 4); // (N+1) i32
    const size_t o_cur  = align16(o_off  + (size_t)(N + 1) * 4); // N i32
    const size_t o_bs   = align16(o_cur  + (size_t)N * 4);       // 128 i32
    const size_t o_ebs  = align16(o_bs   + 512);                 // 128 i32
    const size_t o_sed  = align16(o_ebs  + 512);                 // E int2
    const size_t need   = o_sed + (size_t)E * 8;

    float* h      = (float*)(ws + o_h);
    int*   off    = (int*)  (ws + o_off);
    int*   cursor = (int*)  (ws + o_cur);
    int*   bsum   = (int*)  (ws + o_bs);
    int*   ebsum  = (int*)  (ws + o_ebs);
    int2*  sedge  = (int2*) (ws + o_sed);

    const int nb1 = (N + 1023) / 1024;
    const int mm_blocks = (N + 63) / 64;

    // K1: h = seq @ w_fc ; K2: out = seq @ w_proj + b_proj + bias
    mm_mfma_kernel<<<mm_blocks, 256, 0, stream>>>(seq, w_fc, nullptr, nullptr, h, N, 0);
    mm_mfma_kernel<<<mm_blocks, 256, 0, stream>>>(seq, w_proj, b_proj, bias, out, N, 1);

    if (ws_size >= need && nb1 <= 128) {
        hipMemsetAsync(cursor, 0, (size_t)N * 4, stream);
        hist_kernel<<<2048, 256, 0, stream>>>(edst, cursor, E);
        scan1_kernel<<<nb1, 256, 0, stream>>>(cursor, off + 1, bsum, N);
        scan2_kernel<<<1, 128, 0, stream>>>(bsum, ebsum, nb1);
        addback_kernel<<<nb1, 256, 0, stream>>>(off, cursor, ebsum, N);
        scatter_kernel<<<2048, 256, 0, stream>>>(esrc, edst, vals, cursor, sedge, E);
        const int agg_blocks = (N * 64 + 255) / 256;
        aggregate_kernel<<<agg_blocks, 256, 0, stream>>>(off, sedge, h, out, N);
    } else {
        edge_scatter<<<8192, 256, 0, stream>>>(esrc, edst, vals, h, out, E);
        const int n4 = (N * 128) / 4;
        tanh_kernel<<<(n4 + 255) / 256, 256, 0, stream>>>(out, n4);
    }
}